// Round 9
// baseline (219.615 us; speedup 1.0000x reference)
//
#include <hip/hip_runtime.h>
#include <hip/hip_bf16.h>

// ============================================================================
// ExtraAttention on MI355X (gfx950), bf16 MFMA pipeline.
// R9: = R8 (BK=64 GEMMs, XOR-swizzled LDS) with the LDS overflow fixed:
//     gemm_fused smem restored to 34816 B (V-transpose scratch needs
//     4 waves x 4352 elems x 2 B; R8's 32768 overflowed by 2 KB -> corrupt V).
// Dims: B=4 S=1024 P=128 NX=1024 H=16 dh=64 T=1152
// ============================================================================

typedef __attribute__((ext_vector_type(8))) short bf16x8;
typedef __attribute__((ext_vector_type(4))) float f32x4;

#define MFMA16(a, b, c) __builtin_amdgcn_mfma_f32_16x16x32_bf16((a), (b), (c), 0, 0, 0)

#define GLOAD_LDS16(g, l)                                                  \
    __builtin_amdgcn_global_load_lds(                                      \
        (const __attribute__((address_space(1))) void*)(const void*)(g),   \
        (__attribute__((address_space(3))) void*)(void*)(l), 16, 0, 0)

static __device__ __forceinline__ unsigned short f2bf(float f) {
    union { float f; unsigned int u; } v; v.f = f;
    unsigned int u = v.u;
    return (unsigned short)((u + 0x7fffu + ((u >> 16) & 1u)) >> 16);  // RNE
}

// ---------------------------------------------------------------------------
// Fused: fp32->bf16 converts (x, M) + 3 weight transposes + key-bias build.
static __device__ __forceinline__ void transpose_body(const float* __restrict__ W,
                                                      unsigned short* __restrict__ Wt,
                                                      int K, int N, int bx, int by,
                                                      float (*tile)[33]) {
    int n0 = bx * 32, k0 = by * 32;
    int tx = threadIdx.x & 31, ty = threadIdx.x >> 5;
    #pragma unroll
    for (int r = ty; r < 32; r += 8) tile[r][tx] = W[(size_t)(k0 + r) * N + n0 + tx];
    __syncthreads();
    #pragma unroll
    for (int r = ty; r < 32; r += 8) Wt[(size_t)(n0 + r) * K + k0 + tx] = f2bf(tile[tx][r]);
}

__global__ void prep_all(const float* __restrict__ x, const float* __restrict__ Mem,
                         unsigned short* __restrict__ x_bf, unsigned short* __restrict__ M_bf,
                         const float* __restrict__ W_attn, const float* __restrict__ W_mem,
                         const float* __restrict__ W_proj, unsigned short* __restrict__ Wat,
                         unsigned short* __restrict__ Wmt, unsigned short* __restrict__ Wpt,
                         const float* __restrict__ Mmask, const float* __restrict__ amask,
                         float* __restrict__ biasT) {
    __shared__ float tile[32][33];
    int bid = blockIdx.x;
    if (bid < 4608) {  // converts: 4608*256 threads, 4 elems each
        int i = bid * 256 + threadIdx.x;
        if (i < 1048576) {
            float4 v = ((const float4*)x)[i];
            ushort4 o; o.x = f2bf(v.x); o.y = f2bf(v.y); o.z = f2bf(v.z); o.w = f2bf(v.w);
            ((ushort4*)x_bf)[i] = o;
        } else {
            int j = i - 1048576;
            float4 v = ((const float4*)Mem)[j];
            ushort4 o; o.x = f2bf(v.x); o.y = f2bf(v.y); o.z = f2bf(v.z); o.w = f2bf(v.w);
            ((ushort4*)M_bf)[j] = o;
        }
        return;
    }
    bid -= 4608;
    if (bid < 3072) {
        transpose_body(W_attn, Wat, 1024, 3072, bid % 96, bid / 96, tile);
    } else if (bid < 5120) {
        int t = bid - 3072; transpose_body(W_mem, Wmt, 1024, 2048, t % 64, t / 64, tile);
    } else if (bid < 6144) {
        int t = bid - 5120; transpose_body(W_proj, Wpt, 1024, 1024, t % 32, t / 32, tile);
    } else {
        int i = (bid - 6144) * 256 + threadIdx.x;
        if (i < 4 * 1152) {
            int b = i / 1152, t = i % 1152;
            float v = (t < 128) ? (Mmask[b * 128 + t] - 1.f) * 10000.f
                                : amask[b * 1024 + t - 128];
            biasT[i] = v * 1.4426950408889634f;
        }
    }
}

// ---------------------------------------------------------------------------
// Fused QKV + EKV GEMM, 1024 blocks (exactly 4/CU), BK=64 staging
// (global_load_lds width 16, XOR-swizzled [row][64] LDS: 16B block q of row r
// stored at position q^(r&7) -> conflict-free b128 reads), 16 K-iters.
// Epilogue scatters to Qbuf / Kc[t][64] / Vt[64][t] (v via LDS transpose).
__global__ __launch_bounds__(256, 4) void gemm_fused(
        const unsigned short* __restrict__ x_bf, const unsigned short* __restrict__ Wat,
        const float* __restrict__ b_attn, const unsigned short* __restrict__ M_bf,
        const unsigned short* __restrict__ Wmt, const float* __restrict__ b_mem,
        unsigned short* __restrict__ Qbuf, unsigned short* __restrict__ Kc,
        unsigned short* __restrict__ Vt) {
    __shared__ char smem[34816];   // 2x16KB staging; epilogue scratch needs 34816
    unsigned short* As = (unsigned short*)smem;
    unsigned short* Bs = (unsigned short*)(smem + 16384);
    const int tid = threadIdx.x;
    const int lane = tid & 63, wave = tid >> 6;
    const int quad = lane >> 4, l16 = lane & 15;
    const int srow8 = lane >> 3;                            // row within 8-row chunk
    const int scol = ((lane & 7) ^ (srow8 & 7)) * 8;        // swizzled 16B block
    const int bid = blockIdx.x;

    if (bid < 768) {
        // ---------------- QKV: 128x128 tile, A=x_bf[4096][1024], Bt=Wat[3072][1024]
        const int bm = bid & 31, bn = bid >> 5;             // bn 0..23
        const int wm = (wave & 1) * 64, wn = (wave >> 1) * 64;
        const unsigned short* Abase = x_bf + (size_t)(bm * 128) * 1024;
        const unsigned short* Bbase = Wat + (size_t)(bn * 128) * 1024;
        f32x4 acc[4][4] = {};
        for (int k0 = 0; k0 < 1024; k0 += 64) {
            __syncthreads();
            #pragma unroll
            for (int cc = 0; cc < 8; cc++) {                // 32 chunks of 1KB (8 rows x 64)
                const int c = wave * 8 + cc;
                if (c < 16)
                    GLOAD_LDS16(Abase + (size_t)(c * 8 + srow8) * 1024 + k0 + scol, &As[c * 512]);
                else
                    GLOAD_LDS16(Bbase + (size_t)((c - 16) * 8 + srow8) * 1024 + k0 + scol,
                                &Bs[(c - 16) * 512]);
            }
            __syncthreads();
            #pragma unroll
            for (int h = 0; h < 2; h++) {
                bf16x8 af[4], bf[4];
                #pragma unroll
                for (int i = 0; i < 4; i++) {
                    const int r = wm + i * 16 + l16;
                    af[i] = *(const bf16x8*)&As[r * 64 + ((quad + 4 * h) ^ (r & 7)) * 8];
                }
                #pragma unroll
                for (int j = 0; j < 4; j++) {
                    const int r = wn + j * 16 + l16;
                    bf[j] = *(const bf16x8*)&Bs[r * 64 + ((quad + 4 * h) ^ (r & 7)) * 8];
                }
                #pragma unroll
                for (int i = 0; i < 4; i++)
                    #pragma unroll
                    for (int j = 0; j < 4; j++)
                        acc[i][j] = MFMA16(af[i], bf[j], acc[i][j]);
            }
        }
        float bj[4];
        #pragma unroll
        for (int j = 0; j < 4; j++) bj[j] = b_attn[bn * 128 + wn + j * 16 + l16];
        __syncthreads();  // smem reuse: all waves done with As/Bs
        if (bn < 8) {
            // ---- q -> Qbuf[4096][1024]
            #pragma unroll
            for (int i = 0; i < 4; i++) {
                const int row = bm * 128 + wm + i * 16 + quad * 4;
                #pragma unroll
                for (int j = 0; j < 4; j++) {
                    const int col = bn * 128 + wn + j * 16 + l16;
                    #pragma unroll
                    for (int r = 0; r < 4; r++)
                        Qbuf[(size_t)(row + r) * 1024 + col] = f2bf(acc[i][j][r] + bj[j]);
                }
            }
        } else if (bn < 16) {
            // ---- k -> Kc[bh][t=s+128][d]
            #pragma unroll
            for (int i = 0; i < 4; i++) {
                const int row = bm * 128 + wm + i * 16 + quad * 4;
                const int b = row >> 10, s = row & 1023;
                #pragma unroll
                for (int j = 0; j < 4; j++) {
                    const int c = bn * 128 + wn + j * 16 + l16 - 1024;
                    unsigned short* kd = Kc + (size_t)((b << 4) | (c >> 6)) * 73728 +
                                         (size_t)(s + 128) * 64 + (c & 63);
                    #pragma unroll
                    for (int r = 0; r < 4; r++) kd[(size_t)r * 64] = f2bf(acc[i][j][r] + bj[j]);
                }
            }
        } else {
            // ---- v -> Vt[bh][d][t] via per-wave LDS transpose (64x64, stride 68)
            unsigned short* Tw = (unsigned short*)smem + wave * 4352;  // 4*4352*2 = 34816 B
            #pragma unroll
            for (int i = 0; i < 4; i++)
                #pragma unroll
                for (int j = 0; j < 4; j++)
                    #pragma unroll
                    for (int r = 0; r < 4; r++)
                        Tw[(j * 16 + l16) * 68 + i * 16 + quad * 4 + r] = f2bf(acc[i][j][r] + bj[j]);
            const int vb = (bn - 16) * 128 + wn;            // multiple of 64
            const int h = vb >> 6;
            const int b = bm >> 3, s0 = (bm * 128 + wm) & 1023;
            unsigned short* vd = Vt + (size_t)((b << 4) | h) * 73728 +
                                 (size_t)lane * 1152 + 128 + s0;
            #pragma unroll
            for (int ch = 0; ch < 8; ch++)
                *(bf16x8*)(vd + ch * 8) = *(const bf16x8*)&Tw[lane * 68 + ch * 8];
        }
    } else {
        // ---------------- EKV: 64x64 tile, A=M_bf[512][1024], Bt=Wmt[2048][1024]
        const int t = bid - 768;
        const int bm = t >> 5, bn = t & 31;                 // bm 0..7, bn 0..31
        const int wm = (wave & 1) * 32, wn = (wave >> 1) * 32;
        const unsigned short* Abase = M_bf + (size_t)(bm * 64) * 1024;
        const unsigned short* Bbase = Wmt + (size_t)(bn * 64) * 1024;
        f32x4 acc[2][2] = {};
        for (int k0 = 0; k0 < 1024; k0 += 64) {
            __syncthreads();
            #pragma unroll
            for (int cc = 0; cc < 4; cc++) {                // 16 chunks of 1KB
                const int c = wave * 4 + cc;
                if (c < 8)
                    GLOAD_LDS16(Abase + (size_t)(c * 8 + srow8) * 1024 + k0 + scol, &As[c * 512]);
                else
                    GLOAD_LDS16(Bbase + (size_t)((c - 8) * 8 + srow8) * 1024 + k0 + scol,
                                &Bs[(c - 8) * 512]);
            }
            __syncthreads();
            #pragma unroll
            for (int h = 0; h < 2; h++) {
                bf16x8 af[2], bf[2];
                #pragma unroll
                for (int i = 0; i < 2; i++) {
                    const int r = wm + i * 16 + l16;
                    af[i] = *(const bf16x8*)&As[r * 64 + ((quad + 4 * h) ^ (r & 7)) * 8];
                }
                #pragma unroll
                for (int j = 0; j < 2; j++) {
                    const int r = wn + j * 16 + l16;
                    bf[j] = *(const bf16x8*)&Bs[r * 64 + ((quad + 4 * h) ^ (r & 7)) * 8];
                }
                #pragma unroll
                for (int i = 0; i < 2; i++)
                    #pragma unroll
                    for (int j = 0; j < 2; j++)
                        acc[i][j] = MFMA16(af[i], bf[j], acc[i][j]);
            }
        }
        float bj[2];
        #pragma unroll
        for (int j = 0; j < 2; j++) bj[j] = b_mem[bn * 64 + wn + j * 16 + l16];
        __syncthreads();
        if (bn < 16) {
            // ---- ek -> Kc[bh][t=p][d], p<128
            #pragma unroll
            for (int i = 0; i < 2; i++) {
                const int row = bm * 64 + wm + i * 16 + quad * 4;
                const int b = row >> 7, p = row & 127;
                #pragma unroll
                for (int j = 0; j < 2; j++) {
                    const int c = bn * 64 + wn + j * 16 + l16;
                    unsigned short* kd = Kc + (size_t)((b << 4) | (c >> 6)) * 73728 +
                                         (size_t)p * 64 + (c & 63);
                    #pragma unroll
                    for (int r = 0; r < 4; r++) kd[(size_t)r * 64] = f2bf(acc[i][j][r] + bj[j]);
                }
            }
        } else {
            // ---- ev -> Vt[bh][d][p] via per-wave LDS transpose (32x32, stride 36)
            unsigned short* Tw = (unsigned short*)smem + wave * 1152;
            #pragma unroll
            for (int i = 0; i < 2; i++)
                #pragma unroll
                for (int j = 0; j < 2; j++)
                    #pragma unroll
                    for (int r = 0; r < 4; r++)
                        Tw[(j * 16 + l16) * 36 + i * 16 + quad * 4 + r] = f2bf(acc[i][j][r] + bj[j]);
            const int vb = bn * 64 + wn - 1024;             // multiple of 32
            const int h = vb >> 6, d0 = vb & 63;            // d0 in {0,32}
            const int b = (bm * 64 + wm) >> 7, p0 = (bm * 64 + wm) & 127;
            const int lc = lane >> 1, half = lane & 1;
            unsigned short* vd = Vt + (size_t)((b << 4) | h) * 73728 +
                                 (size_t)(d0 + lc) * 1152 + p0 + half * 16;
            #pragma unroll
            for (int ch = 0; ch < 2; ch++)
                *(bf16x8*)(vd + ch * 8) = *(const bf16x8*)&Tw[lc * 36 + half * 16 + ch * 8];
        }
    }
}

// ---------------------------------------------------------------------------
// Attention (R7, unchanged): 1024 blocks x 128 thr, uniform paired q-groups
// (21 tiles/block), XOR-swizzled K/V LDS, wave0 stages K / wave1 stages V.
__global__ __launch_bounds__(128) void attn_kernel(const unsigned short* __restrict__ Qbuf,
                                                   const unsigned short* __restrict__ Kc,
                                                   const unsigned short* __restrict__ Vt,
                                                   const float* __restrict__ biasT,
                                                   unsigned short* __restrict__ Aout) {
    __shared__ unsigned short Ks[64 * 64];     // swizzled [t][64 k-elems]
    __shared__ unsigned short Vs[64 * 64];     // swizzled [d][64 t-elems]
    __shared__ unsigned short Ps[2][16 * 72];  // per-wave P tile [s][t]
    const int tid = threadIdx.x;
    const int lane = tid & 63, wave = tid >> 6;
    const int quad = lane >> 4, l16 = lane & 15;
    const int blk = blockIdx.x;                 // 1024 = 8 xcd x 8 bh x 16 pair
    const int xcd = blk & 7, idx = blk >> 3;
    const int bh = xcd * 8 + (idx & 7);
    const int pair = idx >> 3;                  // 0..15
    const int h = bh & 15, b = bh >> 4;

    const unsigned short* Kb = Kc + (size_t)bh * 73728;
    const unsigned short* Vb = Vt + (size_t)bh * 73728;
    const float* bias_b = biasT + b * 1152;

    const int srow = lane >> 3;                        // row within 8-row chunk
    const int scol = ((lane & 7) ^ srow) * 8;          // swizzled 16B block
    const int rswz = l16 & 7;                          // read-side swizzle key

    bf16x8 ones;
    #pragma unroll
    for (int j = 0; j < 8; j++) ones[j] = (short)0x3F80;  // bf16 1.0

    #pragma unroll
    for (int phase = 0; phase < 2; phase++) {
        const int qg = phase ? (31 - pair) : pair;     // uniform: tiles(g)+tiles(31-g)=21
        const int qrow0 = qg * 32;
        const int qrow_w = qrow0 + wave * 16;

        bf16x8 qf[2];
        #pragma unroll
        for (int k2 = 0; k2 < 2; k2++)
            qf[k2] = *(const bf16x8*)(Qbuf + (size_t)(b * 1024 + qrow_w + l16) * 1024 +
                                      h * 64 + k2 * 32 + quad * 8);

        f32x4 o[4] = {};
        f32x4 oden = {};
        const int tmax = min(1152, ((qrow0 + 223) >> 6) << 6);

        for (int t0 = 0; t0 < tmax; t0 += 64) {
            __syncthreads();  // all waves done reading previous tile
            if (wave == 0) {  // stage K rows t0..t0+63
                const unsigned short* g = Kb + (size_t)(t0 + srow) * 64 + scol;
                #pragma unroll
                for (int ch = 0; ch < 8; ch++)
                    GLOAD_LDS16(g + (size_t)(ch * 8) * 64, &Ks[ch * 512]);
            } else {          // stage V rows d=0..63, cols t0..t0+63
                const unsigned short* g = Vb + (size_t)srow * 1152 + t0 + scol;
                #pragma unroll
                for (int ch = 0; ch < 8; ch++)
                    GLOAD_LDS16(g + (size_t)(ch * 8) * 1152, &Vs[ch * 512]);
            }
            __syncthreads();  // drains vmcnt -> staged tile visible
            if (t0 <= qrow_w + 143) {
                const bool nomask = (t0 + 63 <= 128 + qrow_w);
                float4 bt[4];
                #pragma unroll
                for (int tn = 0; tn < 4; tn++)
                    bt[tn] = *(const float4*)(bias_b + t0 + tn * 16 + quad * 4);
                const int sg = qrow_w + l16;
                #pragma unroll
                for (int tn = 0; tn < 4; tn++) {
                    bf16x8 kf0 = *(const bf16x8*)&Ks[(tn * 16 + l16) * 64 + (quad ^ rswz) * 8];
                    bf16x8 kf1 = *(const bf16x8*)&Ks[(tn * 16 + l16) * 64 + ((quad + 4) ^ rswz) * 8];
                    f32x4 st = {};
                    st = MFMA16(kf0, qf[0], st);
                    st = MFMA16(kf1, qf[1], st);
                    float p[4];
                    #pragma unroll
                    for (int r = 0; r < 4; r++) {
                        float e = __builtin_amdgcn_exp2f(st[r] * 0.18033688011112042f + bt[tn][r]);
                        if (!nomask) {
                            const int tg = t0 + tn * 16 + quad * 4 + r;
                            e = (tg < 128 || tg - 128 <= sg) ? e : 0.f;
                        }
                        p[r] = e;
                    }
                    union { ushort4 u; __hip_bfloat162 h2[2]; } pk;
                    pk.h2[0] = __float22bfloat162_rn(float2{p[0], p[1]});
                    pk.h2[1] = __float22bfloat162_rn(float2{p[2], p[3]});
                    *(ushort4*)&Ps[wave][l16 * 72 + tn * 16 + quad * 4] = pk.u;
                }
                #pragma unroll
                for (int tk = 0; tk < 2; tk++) {
                    bf16x8 pf = *(const bf16x8*)&Ps[wave][l16 * 72 + tk * 32 + quad * 8];
                    oden = MFMA16(pf, ones, oden);
                    #pragma unroll
                    for (int dn = 0; dn < 4; dn++) {
                        bf16x8 vf = *(const bf16x8*)&Vs[(dn * 16 + l16) * 64 +
                                                        ((tk * 4 + quad) ^ rswz) * 8];
                        o[dn] = MFMA16(pf, vf, o[dn]);
                    }
                }
            }
        }

        // epilogue: o C-layout row s = quad*4+r, col d = dn*16+l16
        #pragma unroll
        for (int r = 0; r < 4; r++) {
            const float inv = 1.f / oden[r];
            const size_t orow = (size_t)(b * 1024 + qrow_w + quad * 4 + r) * 1024 + h * 64;
            #pragma unroll
            for (int dn = 0; dn < 4; dn++)
                Aout[orow + dn * 16 + l16] = f2bf(o[dn][r] * inv);
        }
    }
}

// ---------------------------------------------------------------------------
// proj: 128x64 tiles, 512 blocks, BK=64 swizzled staging, fp32 out.
__global__ __launch_bounds__(256) void gemm_proj(const unsigned short* __restrict__ Abuf,
                                                 const unsigned short* __restrict__ Wpt,
                                                 const float* __restrict__ b_proj,
                                                 float* __restrict__ out) {
    __shared__ unsigned short As[128 * 64];   // 16 KB
    __shared__ unsigned short Bs[64 * 64];    // 8 KB
    const int tid = threadIdx.x;
    const int lane = tid & 63, wave = tid >> 6;
    const int quad = lane >> 4, l16 = lane & 15;
    const int wm = (wave & 1) * 64, wn = (wave >> 1) * 32;
    const int bm = blockIdx.x & 31, bn = blockIdx.x >> 5;
    const int srow8 = lane >> 3;
    const int scol = ((lane & 7) ^ (srow8 & 7)) * 8;
    const unsigned short* Abase = Abuf + (size_t)(bm * 128) * 1024;
    const unsigned short* Bbase = Wpt + (size_t)(bn * 64) * 1024;

    f32x4 acc[4][2] = {};
    for (int k0 = 0; k0 < 1024; k0 += 64) {
        __syncthreads();
        #pragma unroll
        for (int cc = 0; cc < 6; cc++) {                   // 24 chunks of 1KB
            const int c = wave * 6 + cc;
            if (c < 16)
                GLOAD_LDS16(Abase + (size_t)(c * 8 + srow8) * 1024 + k0 + scol, &As[c * 512]);
            else
                GLOAD_LDS16(Bbase + (size_t)((c - 16) * 8 + srow8) * 1024 + k0 + scol,
                            &Bs[(c - 16) * 512]);
        }
        __syncthreads();
        #pragma unroll
        for (int h = 0; h < 2; h++) {
            bf16x8 af[4], bf[2];
            #pragma unroll
            for (int i = 0; i < 4; i++) {
                const int r = wm + i * 16 + l16;
                af[i] = *(const bf16x8*)&As[r * 64 + ((quad + 4 * h) ^ (r & 7)) * 8];
            }
            #pragma unroll
            for (int j = 0; j < 2; j++) {
                const int r = wn + j * 16 + l16;
                bf[j] = *(const bf16x8*)&Bs[r * 64 + ((quad + 4 * h) ^ (r & 7)) * 8];
            }
            #pragma unroll
            for (int i = 0; i < 4; i++)
                #pragma unroll
                for (int j = 0; j < 2; j++)
                    acc[i][j] = MFMA16(af[i], bf[j], acc[i][j]);
        }
    }
    float bj[2];
    #pragma unroll
    for (int j = 0; j < 2; j++) bj[j] = b_proj[bn * 64 + wn + j * 16 + l16];
    #pragma unroll
    for (int i = 0; i < 4; i++) {
        const int row = bm * 128 + wm + i * 16 + quad * 4;
        #pragma unroll
        for (int j = 0; j < 2; j++) {
            const int col = bn * 64 + wn + j * 16 + l16;
            #pragma unroll
            for (int r = 0; r < 4; r++)
                out[(size_t)(row + r) * 1024 + col] = acc[i][j][r] + bj[j];
        }
    }
}

// ---------------------------------------------------------------------------
extern "C" void kernel_launch(void* const* d_in, const int* in_sizes, int n_in,
                              void* d_out, int out_size, void* d_ws, size_t ws_size,
                              hipStream_t stream) {
    const float* x      = (const float*)d_in[0];
    const float* Mem    = (const float*)d_in[1];
    const float* Mmask  = (const float*)d_in[2];
    const float* amask  = (const float*)d_in[3];
    const float* W_attn = (const float*)d_in[4];
    const float* b_attn = (const float*)d_in[5];
    const float* W_mem  = (const float*)d_in[6];
    const float* b_mem  = (const float*)d_in[7];
    const float* W_proj = (const float*)d_in[8];
    const float* b_proj = (const float*)d_in[9];
    float* out = (float*)d_out;

    char* ws = (char*)d_ws;
    unsigned short* x_bf  = (unsigned short*)ws;  ws += (size_t)4096 * 1024 * 2;
    unsigned short* M_bf  = (unsigned short*)ws;  ws += (size_t)512 * 1024 * 2;
    unsigned short* Wat   = (unsigned short*)ws;  ws += (size_t)3072 * 1024 * 2;
    unsigned short* Wmt   = (unsigned short*)ws;  ws += (size_t)2048 * 1024 * 2;
    unsigned short* Wpt   = (unsigned short*)ws;  ws += (size_t)1024 * 1024 * 2;
    unsigned short* Qbuf  = (unsigned short*)ws;  ws += (size_t)4096 * 1024 * 2;
    unsigned short* Abuf  = (unsigned short*)ws;  ws += (size_t)4096 * 1024 * 2;
    unsigned short* Kc    = (unsigned short*)ws;  ws += (size_t)64 * 1152 * 64 * 2;
    unsigned short* Vt    = (unsigned short*)ws;  ws += (size_t)64 * 64 * 1152 * 2;
    float*          biasT = (float*)ws;           ws += (size_t)4 * 1152 * 4;
    // total ws use: ~68 MB

    prep_all<<<10771, 256, 0, stream>>>(x, Mem, x_bf, M_bf, W_attn, W_mem, W_proj,
                                        Wat, Wmt, Wpt, Mmask, amask, biasT);
    gemm_fused<<<1024, 256, 0, stream>>>(x_bf, Wat, b_attn, M_bf, Wmt, b_mem,
                                         Qbuf, Kc, Vt);
    attn_kernel<<<1024, 128, 0, stream>>>(Qbuf, Kc, Vt, biasT, Abuf);
    gemm_proj<<<512, 256, 0, stream>>>(Abuf, Wpt, b_proj, out);
}

// Round 10
// 198.850 us; speedup vs baseline: 1.1044x; 1.1044x over previous
//
#include <hip/hip_runtime.h>
#include <hip/hip_bf16.h>

// ============================================================================
// ExtraAttention on MI355X (gfx950), bf16 MFMA pipeline.
// R10: GEMMs reverted to R7 (BK=32 m97 staging — BK=64 regressed 42->67us);
//      prep transposes upgraded to 64x64 tiles with float4 reads + 16B/lane
//      bf16 writes (4x fewer blocks, wide stores). attn unchanged (R7).
// Dims: B=4 S=1024 P=128 NX=1024 H=16 dh=64 T=1152
// ============================================================================

typedef __attribute__((ext_vector_type(8))) short bf16x8;
typedef __attribute__((ext_vector_type(4))) float f32x4;

#define MFMA16(a, b, c) __builtin_amdgcn_mfma_f32_16x16x32_bf16((a), (b), (c), 0, 0, 0)

#define GLOAD_LDS16(g, l)                                                  \
    __builtin_amdgcn_global_load_lds(                                      \
        (const __attribute__((address_space(1))) void*)(const void*)(g),   \
        (__attribute__((address_space(3))) void*)(void*)(l), 16, 0, 0)

static __device__ __forceinline__ unsigned short f2bf(float f) {
    union { float f; unsigned int u; } v; v.f = f;
    unsigned int u = v.u;
    return (unsigned short)((u + 0x7fffu + ((u >> 16) & 1u)) >> 16);  // RNE
}

// ---------------------------------------------------------------------------
// Fused prep: fp32->bf16 converts (x, M) + 3 weight transposes (64x64 tiles)
// + key-bias build.
static __device__ __forceinline__ void transpose64(const float* __restrict__ W,
                                                   unsigned short* __restrict__ Wt,
                                                   int K, int N, int bx, int by,
                                                   float* tile /* [64][65] */) {
    const int n0 = bx * 64, k0 = by * 64;
    const int tr = threadIdx.x >> 2, tc = (threadIdx.x & 3) * 16;
    // read: 4 x float4 per thread, coalesced 16B/lane
    #pragma unroll
    for (int i = 0; i < 4; i++) {
        float4 v = *(const float4*)&W[(size_t)(k0 + tr) * N + n0 + tc + i * 4];
        tile[tr * 65 + tc + i * 4 + 0] = v.x;
        tile[tr * 65 + tc + i * 4 + 1] = v.y;
        tile[tr * 65 + tc + i * 4 + 2] = v.z;
        tile[tr * 65 + tc + i * 4 + 3] = v.w;
    }
    __syncthreads();
    // write: 16 bf16 per thread (2 x 16B stores), row = output n
    union { ushort4 u4[2]; unsigned short s[8]; } pk[2];
    #pragma unroll
    for (int half = 0; half < 2; half++)
        #pragma unroll
        for (int i = 0; i < 8; i++)
            pk[half].s[i] = f2bf(tile[(tc + half * 8 + i) * 65 + tr]);
    unsigned short* dst = &Wt[(size_t)(n0 + tr) * K + k0 + tc];
    *(ushort4*)(dst + 0) = pk[0].u4[0];
    *(ushort4*)(dst + 4) = pk[0].u4[1];
    *(ushort4*)(dst + 8) = pk[1].u4[0];
    *(ushort4*)(dst + 12) = pk[1].u4[1];
}

__global__ void prep_all(const float* __restrict__ x, const float* __restrict__ Mem,
                         unsigned short* __restrict__ x_bf, unsigned short* __restrict__ M_bf,
                         const float* __restrict__ W_attn, const float* __restrict__ W_mem,
                         const float* __restrict__ W_proj, unsigned short* __restrict__ Wat,
                         unsigned short* __restrict__ Wmt, unsigned short* __restrict__ Wpt,
                         const float* __restrict__ Mmask, const float* __restrict__ amask,
                         float* __restrict__ biasT) {
    __shared__ float tile[64 * 65];
    int bid = blockIdx.x;
    if (bid < 4608) {  // converts: 4608*256 threads, 4 elems each
        int i = bid * 256 + threadIdx.x;
        if (i < 1048576) {
            float4 v = ((const float4*)x)[i];
            ushort4 o; o.x = f2bf(v.x); o.y = f2bf(v.y); o.z = f2bf(v.z); o.w = f2bf(v.w);
            ((ushort4*)x_bf)[i] = o;
        } else {
            int j = i - 1048576;
            float4 v = ((const float4*)Mem)[j];
            ushort4 o; o.x = f2bf(v.x); o.y = f2bf(v.y); o.z = f2bf(v.z); o.w = f2bf(v.w);
            ((ushort4*)M_bf)[j] = o;
        }
        return;
    }
    bid -= 4608;
    if (bid < 768) {        // W_attn: 48 x 16 tiles
        transpose64(W_attn, Wat, 1024, 3072, bid % 48, bid / 48, tile);
    } else if (bid < 1280) { // W_mem: 32 x 16
        int t = bid - 768;  transpose64(W_mem, Wmt, 1024, 2048, t % 32, t / 32, tile);
    } else if (bid < 1536) { // W_proj: 16 x 16
        int t = bid - 1280; transpose64(W_proj, Wpt, 1024, 1024, t % 16, t / 16, tile);
    } else {
        int i = (bid - 1536) * 256 + threadIdx.x;
        if (i < 4 * 1152) {
            int b = i / 1152, t = i % 1152;
            float v = (t < 128) ? (Mmask[b * 128 + t] - 1.f) * 10000.f
                                : amask[b * 1024 + t - 128];
            biasT[i] = v * 1.4426950408889634f;
        }
    }
}

// ---------------------------------------------------------------------------
// Fused QKV + EKV GEMM (R7): 1024 blocks (exactly 4/CU), m97 staging (BK=32,
// global_load_lds width 16, unpadded [row][32] LDS). Epilogue scatters to
// Qbuf / Kc[t][64] / Vt[64][t] (v via per-wave LDS transpose).
__global__ __launch_bounds__(256, 4) void gemm_fused(
        const unsigned short* __restrict__ x_bf, const unsigned short* __restrict__ Wat,
        const float* __restrict__ b_attn, const unsigned short* __restrict__ M_bf,
        const unsigned short* __restrict__ Wmt, const float* __restrict__ b_mem,
        unsigned short* __restrict__ Qbuf, unsigned short* __restrict__ Kc,
        unsigned short* __restrict__ Vt) {
    __shared__ char smem[34816];
    unsigned short* As = (unsigned short*)smem;             // 8 KB staging
    unsigned short* Bs = (unsigned short*)(smem + 8192);    // 8 KB staging
    const int tid = threadIdx.x;
    const int lane = tid & 63, wave = tid >> 6;
    const int quad = lane >> 4, l16 = lane & 15;
    const int crow = lane >> 2, ccol = (lane & 3) * 8;      // staging lane map
    const int bid = blockIdx.x;

    if (bid < 768) {
        // ---------------- QKV: 128x128 tile, A=x_bf[4096][1024], Bt=Wat[3072][1024]
        const int bm = bid & 31, bn = bid >> 5;             // bn 0..23
        const int wm = (wave & 1) * 64, wn = (wave >> 1) * 64;
        const unsigned short* Abase = x_bf + (size_t)(bm * 128 + crow) * 1024 + ccol;
        const unsigned short* Bbase = Wat + (size_t)(bn * 128 + crow) * 1024 + ccol;
        f32x4 acc[4][4] = {};
        for (int k0 = 0; k0 < 1024; k0 += 32) {
            __syncthreads();
            #pragma unroll
            for (int cc = 0; cc < 4; cc++) {
                const int c = wave * 4 + cc;
                if (c < 8) GLOAD_LDS16(Abase + (size_t)(c * 16) * 1024 + k0, &As[c * 512]);
                else       GLOAD_LDS16(Bbase + (size_t)((c - 8) * 16) * 1024 + k0, &Bs[(c - 8) * 512]);
            }
            __syncthreads();
            bf16x8 af[4], bf[4];
            #pragma unroll
            for (int i = 0; i < 4; i++) af[i] = *(const bf16x8*)&As[(wm + i * 16 + l16) * 32 + quad * 8];
            #pragma unroll
            for (int j = 0; j < 4; j++) bf[j] = *(const bf16x8*)&Bs[(wn + j * 16 + l16) * 32 + quad * 8];
            #pragma unroll
            for (int i = 0; i < 4; i++)
                #pragma unroll
                for (int j = 0; j < 4; j++)
                    acc[i][j] = MFMA16(af[i], bf[j], acc[i][j]);
        }
        float bj[4];
        #pragma unroll
        for (int j = 0; j < 4; j++) bj[j] = b_attn[bn * 128 + wn + j * 16 + l16];
        __syncthreads();  // smem reuse: all waves done with As/Bs
        if (bn < 8) {
            // ---- q -> Qbuf[4096][1024]
            #pragma unroll
            for (int i = 0; i < 4; i++) {
                const int row = bm * 128 + wm + i * 16 + quad * 4;
                #pragma unroll
                for (int j = 0; j < 4; j++) {
                    const int col = bn * 128 + wn + j * 16 + l16;
                    #pragma unroll
                    for (int r = 0; r < 4; r++)
                        Qbuf[(size_t)(row + r) * 1024 + col] = f2bf(acc[i][j][r] + bj[j]);
                }
            }
        } else if (bn < 16) {
            // ---- k -> Kc[bh][t=s+128][d]
            #pragma unroll
            for (int i = 0; i < 4; i++) {
                const int row = bm * 128 + wm + i * 16 + quad * 4;
                const int b = row >> 10, s = row & 1023;
                #pragma unroll
                for (int j = 0; j < 4; j++) {
                    const int c = bn * 128 + wn + j * 16 + l16 - 1024;
                    unsigned short* kd = Kc + (size_t)((b << 4) | (c >> 6)) * 73728 +
                                         (size_t)(s + 128) * 64 + (c & 63);
                    #pragma unroll
                    for (int r = 0; r < 4; r++) kd[(size_t)r * 64] = f2bf(acc[i][j][r] + bj[j]);
                }
            }
        } else {
            // ---- v -> Vt[bh][d][t] via per-wave LDS transpose (64x64, stride 68)
            unsigned short* Tw = (unsigned short*)smem + wave * 4352;  // 34816 B total
            #pragma unroll
            for (int i = 0; i < 4; i++)
                #pragma unroll
                for (int j = 0; j < 4; j++)
                    #pragma unroll
                    for (int r = 0; r < 4; r++)
                        Tw[(j * 16 + l16) * 68 + i * 16 + quad * 4 + r] = f2bf(acc[i][j][r] + bj[j]);
            const int vb = (bn - 16) * 128 + wn;            // multiple of 64
            const int h = vb >> 6;
            const int b = bm >> 3, s0 = (bm * 128 + wm) & 1023;
            unsigned short* vd = Vt + (size_t)((b << 4) | h) * 73728 +
                                 (size_t)lane * 1152 + 128 + s0;
            #pragma unroll
            for (int ch = 0; ch < 8; ch++)
                *(bf16x8*)(vd + ch * 8) = *(const bf16x8*)&Tw[lane * 68 + ch * 8];
        }
    } else {
        // ---------------- EKV: 64x64 tile, A=M_bf[512][1024], Bt=Wmt[2048][1024]
        const int t = bid - 768;
        const int bm = t >> 5, bn = t & 31;                 // bm 0..7, bn 0..31
        const int wm = (wave & 1) * 32, wn = (wave >> 1) * 32;
        const unsigned short* Abase = M_bf + (size_t)(bm * 64 + crow) * 1024 + ccol;
        const unsigned short* Bbase = Wmt + (size_t)(bn * 64 + crow) * 1024 + ccol;
        f32x4 acc[2][2] = {};
        for (int k0 = 0; k0 < 1024; k0 += 32) {
            __syncthreads();
            #pragma unroll
            for (int cc = 0; cc < 2; cc++) {
                const int c = wave * 2 + cc;
                if (c < 4) GLOAD_LDS16(Abase + (size_t)(c * 16) * 1024 + k0, &As[c * 512]);
                else       GLOAD_LDS16(Bbase + (size_t)((c - 4) * 16) * 1024 + k0, &Bs[(c - 4) * 512]);
            }
            __syncthreads();
            bf16x8 af[2], bf[2];
            #pragma unroll
            for (int i = 0; i < 2; i++) af[i] = *(const bf16x8*)&As[(wm + i * 16 + l16) * 32 + quad * 8];
            #pragma unroll
            for (int j = 0; j < 2; j++) bf[j] = *(const bf16x8*)&Bs[(wn + j * 16 + l16) * 32 + quad * 8];
            #pragma unroll
            for (int i = 0; i < 2; i++)
                #pragma unroll
                for (int j = 0; j < 2; j++)
                    acc[i][j] = MFMA16(af[i], bf[j], acc[i][j]);
        }
        float bj[2];
        #pragma unroll
        for (int j = 0; j < 2; j++) bj[j] = b_mem[bn * 64 + wn + j * 16 + l16];
        __syncthreads();
        if (bn < 16) {
            // ---- ek -> Kc[bh][t=p][d], p<128
            #pragma unroll
            for (int i = 0; i < 2; i++) {
                const int row = bm * 64 + wm + i * 16 + quad * 4;
                const int b = row >> 7, p = row & 127;
                #pragma unroll
                for (int j = 0; j < 2; j++) {
                    const int c = bn * 64 + wn + j * 16 + l16;
                    unsigned short* kd = Kc + (size_t)((b << 4) | (c >> 6)) * 73728 +
                                         (size_t)p * 64 + (c & 63);
                    #pragma unroll
                    for (int r = 0; r < 4; r++) kd[(size_t)r * 64] = f2bf(acc[i][j][r] + bj[j]);
                }
            }
        } else {
            // ---- ev -> Vt[bh][d][p] via per-wave LDS transpose (32x32, stride 36)
            unsigned short* Tw = (unsigned short*)smem + wave * 1152;
            #pragma unroll
            for (int i = 0; i < 2; i++)
                #pragma unroll
                for (int j = 0; j < 2; j++)
                    #pragma unroll
                    for (int r = 0; r < 4; r++)
                        Tw[(j * 16 + l16) * 36 + i * 16 + quad * 4 + r] = f2bf(acc[i][j][r] + bj[j]);
            const int vb = bn * 64 + wn - 1024;             // multiple of 32
            const int h = vb >> 6, d0 = vb & 63;            // d0 in {0,32}
            const int b = (bm * 64 + wm) >> 7, p0 = (bm * 64 + wm) & 127;
            const int lc = lane >> 1, half = lane & 1;
            unsigned short* vd = Vt + (size_t)((b << 4) | h) * 73728 +
                                 (size_t)(d0 + lc) * 1152 + p0 + half * 16;
            #pragma unroll
            for (int ch = 0; ch < 2; ch++)
                *(bf16x8*)(vd + ch * 8) = *(const bf16x8*)&Tw[lc * 36 + half * 16 + ch * 8];
        }
    }
}

// ---------------------------------------------------------------------------
// Attention (R7, unchanged): 1024 blocks x 128 thr, uniform paired q-groups
// (21 tiles/block), XOR-swizzled K/V LDS, wave0 stages K / wave1 stages V.
__global__ __launch_bounds__(128) void attn_kernel(const unsigned short* __restrict__ Qbuf,
                                                   const unsigned short* __restrict__ Kc,
                                                   const unsigned short* __restrict__ Vt,
                                                   const float* __restrict__ biasT,
                                                   unsigned short* __restrict__ Aout) {
    __shared__ unsigned short Ks[64 * 64];     // swizzled [t][64 k-elems]
    __shared__ unsigned short Vs[64 * 64];     // swizzled [d][64 t-elems]
    __shared__ unsigned short Ps[2][16 * 72];  // per-wave P tile [s][t]
    const int tid = threadIdx.x;
    const int lane = tid & 63, wave = tid >> 6;
    const int quad = lane >> 4, l16 = lane & 15;
    const int blk = blockIdx.x;                 // 1024 = 8 xcd x 8 bh x 16 pair
    const int xcd = blk & 7, idx = blk >> 3;
    const int bh = xcd * 8 + (idx & 7);
    const int pair = idx >> 3;                  // 0..15
    const int h = bh & 15, b = bh >> 4;

    const unsigned short* Kb = Kc + (size_t)bh * 73728;
    const unsigned short* Vb = Vt + (size_t)bh * 73728;
    const float* bias_b = biasT + b * 1152;

    const int srow = lane >> 3;                        // row within 8-row chunk
    const int scol = ((lane & 7) ^ srow) * 8;          // swizzled 16B block
    const int rswz = l16 & 7;                          // read-side swizzle key

    bf16x8 ones;
    #pragma unroll
    for (int j = 0; j < 8; j++) ones[j] = (short)0x3F80;  // bf16 1.0

    #pragma unroll
    for (int phase = 0; phase < 2; phase++) {
        const int qg = phase ? (31 - pair) : pair;     // uniform: tiles(g)+tiles(31-g)=21
        const int qrow0 = qg * 32;
        const int qrow_w = qrow0 + wave * 16;

        bf16x8 qf[2];
        #pragma unroll
        for (int k2 = 0; k2 < 2; k2++)
            qf[k2] = *(const bf16x8*)(Qbuf + (size_t)(b * 1024 + qrow_w + l16) * 1024 +
                                      h * 64 + k2 * 32 + quad * 8);

        f32x4 o[4] = {};
        f32x4 oden = {};
        const int tmax = min(1152, ((qrow0 + 223) >> 6) << 6);

        for (int t0 = 0; t0 < tmax; t0 += 64) {
            __syncthreads();  // all waves done reading previous tile
            if (wave == 0) {  // stage K rows t0..t0+63
                const unsigned short* g = Kb + (size_t)(t0 + srow) * 64 + scol;
                #pragma unroll
                for (int ch = 0; ch < 8; ch++)
                    GLOAD_LDS16(g + (size_t)(ch * 8) * 64, &Ks[ch * 512]);
            } else {          // stage V rows d=0..63, cols t0..t0+63
                const unsigned short* g = Vb + (size_t)srow * 1152 + t0 + scol;
                #pragma unroll
                for (int ch = 0; ch < 8; ch++)
                    GLOAD_LDS16(g + (size_t)(ch * 8) * 1152, &Vs[ch * 512]);
            }
            __syncthreads();  // drains vmcnt -> staged tile visible
            if (t0 <= qrow_w + 143) {
                const bool nomask = (t0 + 63 <= 128 + qrow_w);
                float4 bt[4];
                #pragma unroll
                for (int tn = 0; tn < 4; tn++)
                    bt[tn] = *(const float4*)(bias_b + t0 + tn * 16 + quad * 4);
                const int sg = qrow_w + l16;
                #pragma unroll
                for (int tn = 0; tn < 4; tn++) {
                    bf16x8 kf0 = *(const bf16x8*)&Ks[(tn * 16 + l16) * 64 + (quad ^ rswz) * 8];
                    bf16x8 kf1 = *(const bf16x8*)&Ks[(tn * 16 + l16) * 64 + ((quad + 4) ^ rswz) * 8];
                    f32x4 st = {};
                    st = MFMA16(kf0, qf[0], st);
                    st = MFMA16(kf1, qf[1], st);
                    float p[4];
                    #pragma unroll
                    for (int r = 0; r < 4; r++) {
                        float e = __builtin_amdgcn_exp2f(st[r] * 0.18033688011112042f + bt[tn][r]);
                        if (!nomask) {
                            const int tg = t0 + tn * 16 + quad * 4 + r;
                            e = (tg < 128 || tg - 128 <= sg) ? e : 0.f;
                        }
                        p[r] = e;
                    }
                    union { ushort4 u; __hip_bfloat162 h2[2]; } pk;
                    pk.h2[0] = __float22bfloat162_rn(float2{p[0], p[1]});
                    pk.h2[1] = __float22bfloat162_rn(float2{p[2], p[3]});
                    *(ushort4*)&Ps[wave][l16 * 72 + tn * 16 + quad * 4] = pk.u;
                }
                #pragma unroll
                for (int tk = 0; tk < 2; tk++) {
                    bf16x8 pf = *(const bf16x8*)&Ps[wave][l16 * 72 + tk * 32 + quad * 8];
                    oden = MFMA16(pf, ones, oden);
                    #pragma unroll
                    for (int dn = 0; dn < 4; dn++) {
                        bf16x8 vf = *(const bf16x8*)&Vs[(dn * 16 + l16) * 64 +
                                                        ((tk * 4 + quad) ^ rswz) * 8];
                        o[dn] = MFMA16(pf, vf, o[dn]);
                    }
                }
            }
        }

        // epilogue: o C-layout row s = quad*4+r, col d = dn*16+l16
        #pragma unroll
        for (int r = 0; r < 4; r++) {
            const float inv = 1.f / oden[r];
            const size_t orow = (size_t)(b * 1024 + qrow_w + quad * 4 + r) * 1024 + h * 64;
            #pragma unroll
            for (int dn = 0; dn < 4; dn++)
                Aout[orow + dn * 16 + l16] = f2bf(o[dn][r] * inv);
        }
    }
}

// ---------------------------------------------------------------------------
// proj (R7): 128x64 tiles, 512 blocks, BK=32 m97 staging, fp32 out.
__global__ __launch_bounds__(256) void gemm_proj(const unsigned short* __restrict__ Abuf,
                                                 const unsigned short* __restrict__ Wpt,
                                                 const float* __restrict__ b_proj,
                                                 float* __restrict__ out) {
    __shared__ unsigned short As[128 * 32];
    __shared__ unsigned short Bs[64 * 32];
    const int tid = threadIdx.x;
    const int lane = tid & 63, wave = tid >> 6;
    const int quad = lane >> 4, l16 = lane & 15;
    const int wm = (wave & 1) * 64, wn = (wave >> 1) * 32;
    const int bm = blockIdx.x & 31, bn = blockIdx.x >> 5;
    const int crow = lane >> 2, ccol = (lane & 3) * 8;
    const unsigned short* Abase = Abuf + (size_t)(bm * 128 + crow) * 1024 + ccol;
    const unsigned short* Bbase = Wpt + (size_t)(bn * 64 + crow) * 1024 + ccol;

    f32x4 acc[4][2] = {};
    for (int k0 = 0; k0 < 1024; k0 += 32) {
        __syncthreads();
        #pragma unroll
        for (int cc = 0; cc < 3; cc++) {
            const int c = wave * 3 + cc;
            if (c < 8) GLOAD_LDS16(Abase + (size_t)(c * 16) * 1024 + k0, &As[c * 512]);
            else if (c < 12) GLOAD_LDS16(Bbase + (size_t)((c - 8) * 16) * 1024 + k0, &Bs[(c - 8) * 512]);
        }
        __syncthreads();
        bf16x8 af[4], bf[2];
        #pragma unroll
        for (int i = 0; i < 4; i++) af[i] = *(const bf16x8*)&As[(wm + i * 16 + l16) * 32 + quad * 8];
        #pragma unroll
        for (int j = 0; j < 2; j++) bf[j] = *(const bf16x8*)&Bs[(wn + j * 16 + l16) * 32 + quad * 8];
        #pragma unroll
        for (int i = 0; i < 4; i++)
            #pragma unroll
            for (int j = 0; j < 2; j++)
                acc[i][j] = MFMA16(af[i], bf[j], acc[i][j]);
    }
    float bj[2];
    #pragma unroll
    for (int j = 0; j < 2; j++) bj[j] = b_proj[bn * 64 + wn + j * 16 + l16];
    #pragma unroll
    for (int i = 0; i < 4; i++) {
        const int row = bm * 128 + wm + i * 16 + quad * 4;
        #pragma unroll
        for (int j = 0; j < 2; j++) {
            const int col = bn * 64 + wn + j * 16 + l16;
            #pragma unroll
            for (int r = 0; r < 4; r++)
                out[(size_t)(row + r) * 1024 + col] = acc[i][j][r] + bj[j];
        }
    }
}

// ---------------------------------------------------------------------------
extern "C" void kernel_launch(void* const* d_in, const int* in_sizes, int n_in,
                              void* d_out, int out_size, void* d_ws, size_t ws_size,
                              hipStream_t stream) {
    const float* x      = (const float*)d_in[0];
    const float* Mem    = (const float*)d_in[1];
    const float* Mmask  = (const float*)d_in[2];
    const float* amask  = (const float*)d_in[3];
    const float* W_attn = (const float*)d_in[4];
    const float* b_attn = (const float*)d_in[5];
    const float* W_mem  = (const float*)d_in[6];
    const float* b_mem  = (const float*)d_in[7];
    const float* W_proj = (const float*)d_in[8];
    const float* b_proj = (const float*)d_in[9];
    float* out = (float*)d_out;

    char* ws = (char*)d_ws;
    unsigned short* x_bf  = (unsigned short*)ws;  ws += (size_t)4096 * 1024 * 2;
    unsigned short* M_bf  = (unsigned short*)ws;  ws += (size_t)512 * 1024 * 2;
    unsigned short* Wat   = (unsigned short*)ws;  ws += (size_t)3072 * 1024 * 2;
    unsigned short* Wmt   = (unsigned short*)ws;  ws += (size_t)2048 * 1024 * 2;
    unsigned short* Wpt   = (unsigned short*)ws;  ws += (size_t)1024 * 1024 * 2;
    unsigned short* Qbuf  = (unsigned short*)ws;  ws += (size_t)4096 * 1024 * 2;
    unsigned short* Abuf  = (unsigned short*)ws;  ws += (size_t)4096 * 1024 * 2;
    unsigned short* Kc    = (unsigned short*)ws;  ws += (size_t)64 * 1152 * 64 * 2;
    unsigned short* Vt    = (unsigned short*)ws;  ws += (size_t)64 * 64 * 1152 * 2;
    float*          biasT = (float*)ws;           ws += (size_t)4 * 1152 * 4;
    // total ws use: ~68 MB

    prep_all<<<6163, 256, 0, stream>>>(x, Mem, x_bf, M_bf, W_attn, W_mem, W_proj,
                                       Wat, Wmt, Wpt, Mmask, amask, biasT);
    gemm_fused<<<1024, 256, 0, stream>>>(x_bf, Wat, b_attn, M_bf, Wmt, b_mem,
                                         Qbuf, Kc, Vt);
    attn_kernel<<<1024, 128, 0, stream>>>(Qbuf, Kc, Vt, biasT, Abuf);
    gemm_proj<<<512, 256, 0, stream>>>(Abuf, Wpt, b_proj, out);
}